// Round 9
// baseline (61.243 us; speedup 1.0000x reference)
//
#include <hip/hip_runtime.h>
#include <math.h>

// HeteAttention capsule routing, MI355X — bf16-packed register-resident z +
// full-cover register prefetch of the next batch element (software pipeline
// across b; loads issued a whole b-round before use).
// B=4096, n=1, N=128, F=8 facets, D=16, n_iter=4, C=F*D=128.
// Grid 1024 blocks x 512 thr (8 waves); NB=4 b's per block.
// Lane map (per wave): cg = lane&15 owns channels c = cg*8..cg*8+7; lane
// bit0 = half of facet f = cg>>1; kgl = lane>>4; kq = wave*4+kgl in [0,32)
// owns k = kq*4..kq*4+3.
// z: loaded fp32 into raw regs (32 VGPR), L2-normalized per (k,facet),
// packed to bf16 pairs (v_cvt_pk_bf16_f32) -> zp = 16 VGPR for compute.
// Raw regs are DEAD during the 4 routing iterations -> next b's 8 dwordx4
// issue at it=0 top (cover ~= 3 iterations >> HBM latency). Plain register
// loads cross __syncthreads with no vmcnt drain (only LDS-writing DMA
// drains), so the prefetch survives all 8 barriers of the b-round.
// Reductions: DPP quad_perm/mirrors (bit0 + softmax facet bits 1..3),
// permlane16/32 swaps (kgl). 8 wave-partials combined in LDS by threads
// 0..127. Softmax max-pass dropped (|logit|<=1, shift-invariant); exp2
// with log2e folded into broadcast u. absmax ~0.0156 (bf16 z), thr 0.0597.

#define CC 128
#define NB 4
#define ZSZ (128 * CC)
#define LOG2E 1.44269504088896340736f

typedef float f32x2 __attribute__((ext_vector_type(2)));
typedef unsigned u32x2 __attribute__((ext_vector_type(2)));

template<int CTRL>
__device__ __forceinline__ float dpp_add(float x) {
    int y = __builtin_amdgcn_update_dpp(0, __float_as_int(x), CTRL, 0xF, 0xF, true);
    return x + __int_as_float(y);
}
#define DPP_XOR1 0xB1   // quad_perm [1,0,3,2]
#define DPP_XOR2 0x4E   // quad_perm [2,3,0,1]
#define DPP_HMIR 0x141  // row_half_mirror (^7; ^4 given uniform bits 0,1)
#define DPP_MIR  0x140  // row_mirror      (^15; ^8 given uniform bits 0..2)

__device__ __forceinline__ f32x2 xor16_add2(f32x2 v) {
    u32x2 r0 = __builtin_amdgcn_permlane16_swap(__float_as_uint(v.x), __float_as_uint(v.x), false, false);
    u32x2 r1 = __builtin_amdgcn_permlane16_swap(__float_as_uint(v.y), __float_as_uint(v.y), false, false);
    f32x2 o;
    o.x = __uint_as_float(r0.x) + __uint_as_float(r0.y);
    o.y = __uint_as_float(r1.x) + __uint_as_float(r1.y);
    return o;
}
__device__ __forceinline__ f32x2 xor32_add2(f32x2 v) {
    u32x2 r0 = __builtin_amdgcn_permlane32_swap(__float_as_uint(v.x), __float_as_uint(v.x), false, false);
    u32x2 r1 = __builtin_amdgcn_permlane32_swap(__float_as_uint(v.y), __float_as_uint(v.y), false, false);
    f32x2 o;
    o.x = __uint_as_float(r0.x) + __uint_as_float(r0.y);
    o.y = __uint_as_float(r1.x) + __uint_as_float(r1.y);
    return o;
}
__device__ __forceinline__ float rsq_guard(float s) {
    return __builtin_amdgcn_rsqf(fmaxf(s, 1e-24f));
}
__device__ __forceinline__ unsigned pack_bf16(float lo, float hi) {
    unsigned r;
    asm("v_cvt_pk_bf16_f32 %0, %1, %2" : "=v"(r) : "v"(lo), "v"(hi));
    return r;
}
__device__ __forceinline__ f32x2 unpack_bf16(unsigned u) {
    f32x2 r;
    r.x = __uint_as_float(u << 16);
    r.y = __uint_as_float(u & 0xFFFF0000u);
    return r;
}

__global__ __launch_bounds__(512, 5)
void hete_routing_kernel(const float* __restrict__ feat,   // [B, 128]
                         const float* __restrict__ mp,     // [B, 128, 128]
                         float* __restrict__ out)          // [B, 128]
{
    __shared__ float part[8][CC];   // 4 KB: per-wave partials
    __shared__ float u_s[CC];       // 512 B: broadcast u (pre-scaled log2e)

    const int t = threadIdx.x;
    const int wave = t >> 6;          // 0..7
    const int lane = t & 63;
    const int cg = lane & 15;
    const int kgl = lane >> 4;        // 0..3
    const int kq = wave * 4 + kgl;    // 0..31, owns k = kq*4 .. kq*4+3
    const int c0 = cg * 8;
    const int b0 = blockIdx.x * NB;

    const float* zb = mp + (size_t)b0 * ZSZ + kq * 4 * CC + c0;

    // ---- raw staging regs: b0's z slice (8 dwordx4 = 32 VGPR) ----
    float4 A[4], Bv[4];
#pragma unroll
    for (int kk = 0; kk < 4; ++kk) {
        A[kk]  = *reinterpret_cast<const float4*>(zb + kk * CC);
        Bv[kk] = *reinterpret_cast<const float4*>(zb + kk * CC + 4);
    }
    float xv = 0.f;
    if (t < CC) xv = feat[(size_t)b0 * CC + t];

#pragma unroll 1
    for (int i = 0; i < NB; ++i) {
        // ---- normalize raw per (k,facet), pack to bf16 (raw dead after) ----
        unsigned zp[4][4];
#pragma unroll
        for (int kk = 0; kk < 4; ++kk) {
            float s = A[kk].x * A[kk].x + A[kk].y * A[kk].y
                    + A[kk].z * A[kk].z + A[kk].w * A[kk].w
                    + Bv[kk].x * Bv[kk].x + Bv[kk].y * Bv[kk].y
                    + Bv[kk].z * Bv[kk].z + Bv[kk].w * Bv[kk].w;
            s = dpp_add<DPP_XOR1>(s);
            const float inv = rsq_guard(s);
            zp[kk][0] = pack_bf16(A[kk].x * inv,  A[kk].y * inv);
            zp[kk][1] = pack_bf16(A[kk].z * inv,  A[kk].w * inv);
            zp[kk][2] = pack_bf16(Bv[kk].x * inv, Bv[kk].y * inv);
            zp[kk][3] = pack_bf16(Bv[kk].z * inv, Bv[kk].w * inv);
        }

        // ---- combiner threads (t<128): x_hat via facet DPP reduce ----
        float xh = 0.f;
        if (t < CC) {
            float s = xv * xv;
            s = dpp_add<DPP_XOR1>(s);
            s = dpp_add<DPP_XOR2>(s);
            s = dpp_add<DPP_HMIR>(s);
            s = dpp_add<DPP_MIR>(s);
            xh = xv * rsq_guard(s);
            u_s[t] = xh * LOG2E;
        }
        __syncthreads();

        // ---- routing iterations ----
#pragma unroll
        for (int it = 0; it < 4; ++it) {
            // prefetch next b's z + x into the dead raw regs, a full
            // b-round ahead of use (register loads survive barriers).
            if (it == 0 && i + 1 < NB) {
                const float* zn = zb + (size_t)(i + 1) * ZSZ;
#pragma unroll
                for (int kk = 0; kk < 4; ++kk) {
                    A[kk]  = *reinterpret_cast<const float4*>(zn + kk * CC);
                    Bv[kk] = *reinterpret_cast<const float4*>(zn + kk * CC + 4);
                }
                if (t < CC) xv = feat[(size_t)(b0 + i + 1) * CC + t];
            }

            // broadcast u (pre-scaled by log2e) from LDS
            f32x2 ur[4];
            {
                const float4 Ua = *reinterpret_cast<const float4*>(&u_s[c0]);
                const float4 Ub = *reinterpret_cast<const float4*>(&u_s[c0 + 4]);
                ur[0] = f32x2{Ua.x, Ua.y};  ur[1] = f32x2{Ua.z, Ua.w};
                ur[2] = f32x2{Ub.x, Ub.y};  ur[3] = f32x2{Ub.z, Ub.w};
            }

            // fused logit -> softmax -> weighted-sum per owned k
            f32x2 pu[4] = {f32x2{0.f,0.f}, f32x2{0.f,0.f}, f32x2{0.f,0.f}, f32x2{0.f,0.f}};
#pragma unroll
            for (int kk = 0; kk < 4; ++kk) {
                const f32x2 z0 = unpack_bf16(zp[kk][0]);
                const f32x2 z1 = unpack_bf16(zp[kk][1]);
                const f32x2 z2 = unpack_bf16(zp[kk][2]);
                const f32x2 z3 = unpack_bf16(zp[kk][3]);
                f32x2 acc = z0 * ur[0];
                acc += z1 * ur[1];
                acc += z2 * ur[2];
                acc += z3 * ur[3];
                const float l = dpp_add<DPP_XOR1>(acc.x + acc.y);   // 16-d dot
                const float e = __builtin_amdgcn_exp2f(l);
                float su = dpp_add<DPP_XOR2>(e);                    // facet sum
                su = dpp_add<DPP_HMIR>(su);
                su = dpp_add<DPP_MIR>(su);
                const float wk = e * __builtin_amdgcn_rcpf(su);
                const f32x2 ws = {wk, wk};
                pu[0] += z0 * ws;
                pu[1] += z1 * ws;
                pu[2] += z2 * ws;
                pu[3] += z3 * ws;
            }
            // reduce over kgl (lane bits 4,5) via permlane swaps (VALU)
#pragma unroll
            for (int j = 0; j < 4; ++j) {
                pu[j] = xor16_add2(pu[j]);
                pu[j] = xor32_add2(pu[j]);
            }
            if (kgl == 0) {
                float* dst = &part[wave][c0];
                *reinterpret_cast<float4*>(dst)     = make_float4(pu[0].x, pu[0].y, pu[1].x, pu[1].y);
                *reinterpret_cast<float4*>(dst + 4) = make_float4(pu[2].x, pu[2].y, pu[3].x, pu[3].y);
            }
            __syncthreads();

            // combiners: sum 8 wave-partials + x residual; norm or emit
            if (t < CC) {
                float un = xh;
#pragma unroll
                for (int j = 0; j < 8; ++j) un += part[j][t];
                if (it < 3) {
                    float s = un * un;
                    s = dpp_add<DPP_XOR1>(s);
                    s = dpp_add<DPP_XOR2>(s);
                    s = dpp_add<DPP_HMIR>(s);
                    s = dpp_add<DPP_MIR>(s);
                    u_s[t] = un * rsq_guard(s) * LOG2E;
                } else {
                    out[(size_t)(b0 + i) * CC + t] = un;
                }
            }
            if (it < 3) __syncthreads();
        }
    }
}

extern "C" void kernel_launch(void* const* d_in, const int* in_sizes, int n_in,
                              void* d_out, int out_size, void* d_ws, size_t ws_size,
                              hipStream_t stream) {
    const float* feat = (const float*)d_in[0];   // features [B,1,128] fp32
    const float* mp   = (const float*)d_in[1];   // metapath [B,1,128,128] fp32
    float* out = (float*)d_out;                  // [B,128] fp32
    const int B = in_sizes[0] / CC;              // 4096
    hete_routing_kernel<<<B / NB, 512, 0, stream>>>(feat, mp, out);
}

// Round 10
// 52.608 us; speedup vs baseline: 1.1641x; 1.1641x over previous
//
#include <hip/hip_runtime.h>
#include <math.h>

// HeteAttention capsule routing, MI355X — bf16-packed register-resident z
// with PERFECTLY LINEAR global loads (each wave reads one contiguous 8 KB
// span; block reads contiguous 64 KB) to lift memory-controller efficiency.
// B=4096, n=1, N=128, F=8 facets, D=16, n_iter=4, C=F*D=128.
// Grid 4096 blocks x 512 thr (8 waves); one b per block.
// Lane map: lane l, reg-row j (0..7) holds k = w*16 + 2j + (l>>5),
// channels c = (l&31)*4 .. +3 (4 channels). Facet f = (l&31)>>2.
//   facet 16-d dot:    XOR1 + XOR2   (l bits 0,1)
//   softmax facet-sum: HMIR + MIR + permlane16 (l bits 2,3,4; lower bits
//                      uniform after the dot reduce so ^7==^4, ^15==^8)
//   k-reduce:          permlane32    (l bit 5)
// z normalized fp32 then packed to bf16 pairs (v_cvt_pk_bf16_f32): zp = 16
// VGPR. Softmax max-pass dropped (|logit|<=1); exp2 with log2e folded into
// broadcast u. Combine: 8 wave-partials in LDS, threads 0..127 sum + norm.
// absmax ~0.0156 (bf16 z) vs threshold 0.0597.

#define CC 128
#define LOG2E 1.44269504088896340736f

typedef float f32x2 __attribute__((ext_vector_type(2)));
typedef unsigned u32x2 __attribute__((ext_vector_type(2)));

template<int CTRL>
__device__ __forceinline__ float dpp_add(float x) {
    int y = __builtin_amdgcn_update_dpp(0, __float_as_int(x), CTRL, 0xF, 0xF, true);
    return x + __int_as_float(y);
}
#define DPP_XOR1 0xB1   // quad_perm [1,0,3,2]
#define DPP_XOR2 0x4E   // quad_perm [2,3,0,1]
#define DPP_HMIR 0x141  // row_half_mirror (^7; ==^4 when bits 0,1 uniform)
#define DPP_MIR  0x140  // row_mirror      (^15; ==^8 when bits 0..2 uniform)

__device__ __forceinline__ float xor16_add(float v) {
    u32x2 r = __builtin_amdgcn_permlane16_swap(__float_as_uint(v), __float_as_uint(v), false, false);
    return __uint_as_float(r.x) + __uint_as_float(r.y);
}
__device__ __forceinline__ f32x2 xor32_add2(f32x2 v) {
    u32x2 r0 = __builtin_amdgcn_permlane32_swap(__float_as_uint(v.x), __float_as_uint(v.x), false, false);
    u32x2 r1 = __builtin_amdgcn_permlane32_swap(__float_as_uint(v.y), __float_as_uint(v.y), false, false);
    f32x2 o;
    o.x = __uint_as_float(r0.x) + __uint_as_float(r0.y);
    o.y = __uint_as_float(r1.x) + __uint_as_float(r1.y);
    return o;
}
__device__ __forceinline__ float rsq_guard(float s) {
    return __builtin_amdgcn_rsqf(fmaxf(s, 1e-24f));
}
__device__ __forceinline__ unsigned pack_bf16(float lo, float hi) {
    unsigned r;
    asm("v_cvt_pk_bf16_f32 %0, %1, %2" : "=v"(r) : "v"(lo), "v"(hi));
    return r;
}
__device__ __forceinline__ f32x2 unpack_bf16(unsigned u) {
    f32x2 r;
    r.x = __uint_as_float(u << 16);
    r.y = __uint_as_float(u & 0xFFFF0000u);
    return r;
}

__global__ __launch_bounds__(512, 8)
void hete_routing_kernel(const float* __restrict__ feat,   // [B, 128]
                         const float* __restrict__ mp,     // [B, 128, 128]
                         float* __restrict__ out)          // [B, 128]
{
    __shared__ float part[8][CC];   // 4 KB: per-wave k-partials
    __shared__ float u_s[CC];       // 512 B: broadcast u (pre-scaled log2e)

    const int t = threadIdx.x;
    const int w = t >> 6;             // wave 0..7
    const int l = t & 63;
    const int q = l & 31;             // channel-group: c = q*4..q*4+3
    const int b = blockIdx.x;

    // ---- stage z: 8 perfectly-linear float4 loads per lane ----
    // float index = w*2048 + j*256 + l*4  (wave = contiguous 8 KB)
    const float* zg = mp + (size_t)b * (128 * CC) + w * 2048 + l * 4;
    float4 raw[8];
#pragma unroll
    for (int j = 0; j < 8; ++j)
        raw[j] = *reinterpret_cast<const float4*>(zg + j * 256);

    // ---- combiner threads (t<128): x channel; x_hat via facet DPP reduce ----
    float xh = 0.f;
    if (t < CC) {
        const float xv = feat[(size_t)b * CC + t];
        float s = xv * xv;
        s = dpp_add<DPP_XOR1>(s);
        s = dpp_add<DPP_XOR2>(s);
        s = dpp_add<DPP_HMIR>(s);
        s = dpp_add<DPP_MIR>(s);
        xh = xv * rsq_guard(s);
        u_s[t] = xh * LOG2E;
    }

    // ---- normalize each row's (k,facet) and pack to bf16 ----
    // facet sumsq: 4 local ch + lanes ^1,^2 (same k, same facet).
    unsigned zp[8][2];
#pragma unroll
    for (int j = 0; j < 8; ++j) {
        float s = raw[j].x * raw[j].x + raw[j].y * raw[j].y
                + raw[j].z * raw[j].z + raw[j].w * raw[j].w;
        s = dpp_add<DPP_XOR1>(s);
        s = dpp_add<DPP_XOR2>(s);
        const float inv = rsq_guard(s);
        zp[j][0] = pack_bf16(raw[j].x * inv, raw[j].y * inv);
        zp[j][1] = pack_bf16(raw[j].z * inv, raw[j].w * inv);
    }
    __syncthreads();

    // ---- routing iterations ----
#pragma unroll
    for (int it = 0; it < 4; ++it) {
        // broadcast u (pre-scaled log2e): this lane's 4 channels
        f32x2 ur0, ur1;
        {
            const float4 U = *reinterpret_cast<const float4*>(&u_s[q * 4]);
            ur0 = f32x2{U.x, U.y};
            ur1 = f32x2{U.z, U.w};
        }

        // fused logit -> softmax -> weighted-sum per owned k-row
        f32x2 pu0 = {0.f, 0.f}, pu1 = {0.f, 0.f};
#pragma unroll
        for (int j = 0; j < 8; ++j) {
            const f32x2 z0 = unpack_bf16(zp[j][0]);
            const f32x2 z1 = unpack_bf16(zp[j][1]);
            f32x2 acc = z0 * ur0;
            acc += z1 * ur1;
            float d = acc.x + acc.y;          // 4-ch partial dot
            d = dpp_add<DPP_XOR1>(d);         // 8-ch
            d = dpp_add<DPP_XOR2>(d);         // full 16-ch logit (x log2e)
            const float e = __builtin_amdgcn_exp2f(d);
            float su = dpp_add<DPP_HMIR>(e);  // facet bit 2
            su = dpp_add<DPP_MIR>(su);        // facet bit 3
            su = xor16_add(su);               // facet bit 4
            const float wk = e * __builtin_amdgcn_rcpf(su);
            const f32x2 ws = {wk, wk};
            pu0 += z0 * ws;
            pu1 += z1 * ws;
        }
        // k-reduce over l bit 5 (even/odd k interleave)
        pu0 = xor32_add2(pu0);
        pu1 = xor32_add2(pu1);
        if (l < 32) {
            *reinterpret_cast<float4*>(&part[w][q * 4]) =
                make_float4(pu0.x, pu0.y, pu1.x, pu1.y);
        }
        __syncthreads();

        // combiners: sum 8 wave-partials + x residual; norm or emit
        if (t < CC) {
            float un = xh;
#pragma unroll
            for (int j = 0; j < 8; ++j) un += part[j][t];
            if (it < 3) {
                float s = un * un;
                s = dpp_add<DPP_XOR1>(s);
                s = dpp_add<DPP_XOR2>(s);
                s = dpp_add<DPP_HMIR>(s);
                s = dpp_add<DPP_MIR>(s);
                u_s[t] = un * rsq_guard(s) * LOG2E;
            } else {
                out[(size_t)b * CC + t] = un;
            }
        }
        if (it < 3) __syncthreads();
    }
}

extern "C" void kernel_launch(void* const* d_in, const int* in_sizes, int n_in,
                              void* d_out, int out_size, void* d_ws, size_t ws_size,
                              hipStream_t stream) {
    const float* feat = (const float*)d_in[0];   // features [B,1,128] fp32
    const float* mp   = (const float*)d_in[1];   // metapath [B,1,128,128] fp32
    float* out = (float*)d_out;                  // [B,128] fp32
    const int B = in_sizes[0] / CC;              // 4096
    hete_routing_kernel<<<B, 512, 0, stream>>>(feat, mp, out);
}